// Round 1
// baseline (311.334 us; speedup 1.0000x reference)
//
#include <hip/hip_runtime.h>

// GAT layer N=50000, E=800000, DIN=DOUT=128, H=4.
// ALGEBRAIC SIMPLIFICATION: softmax weights per (node,head) sum to exactly 1,
// so attn_w[n,h] = 1/deg[n] for every head and
//   out[n] = (1/deg[n]) * sum_{e: col[e]=n} v[row[e]],  v = x @ Wv^T + bv.
// Wq,bq,Wk,bk,att do not affect the output.

#define N_NODES 50000
#define N_EDGES 800000

// ---- workspace layout (bytes) ----
// v      : float[50000*128]  @ 0           (25,600,000)
// deg    : int[50000]        @ 25,600,000  (200,000)
// cursor : int[50000]        @ 25,800,000  (200,000)   <- deg+cursor zeroed by one memset
// start  : int[50000]        @ 26,000,000
// bsum   : int[256]          @ 26,200,000
// boff   : int[256]          @ 26,201,024
// flag   : int[1]            @ 26,202,048
// eidx   : int[800000]       @ 26,203,072  (3,200,000)
// total ~29.4 MB

// edge_index may arrive as int32 (per harness doc) or raw int64 (reference dtype).
// If int64: values < 50000 so every high dword is 0 -> detect via odd int32 slots.
__device__ __forceinline__ void load_edge(const int* __restrict__ ei, int wide, int e,
                                          int& r, int& c) {
    if (wide) { r = ei[2 * e]; c = ei[2 * N_EDGES + 2 * e]; }
    else      { r = ei[e];     c = ei[N_EDGES + e]; }
}

__global__ void detect_kernel(const int* __restrict__ ei, int* __restrict__ flag) {
    int t = threadIdx.x;  // 64 threads
    int nz = (ei[2 * t + 1] != 0) ? 1 : 0;
    unsigned long long b = __ballot(nz);
    if (t == 0) *flag = (b == 0ULL) ? 1 : 0;
}

__global__ __launch_bounds__(256) void deg_kernel(const int* __restrict__ ei,
                                                  const int* __restrict__ flag,
                                                  int* __restrict__ deg) {
    int e = blockIdx.x * 256 + threadIdx.x;
    if (e < N_EDGES) {
        int r, c;
        load_edge(ei, *flag, e, r, c);
        atomicAdd(&deg[c], 1);
    }
}

__global__ __launch_bounds__(256) void scan_a(const int* __restrict__ deg,
                                              int* __restrict__ bsum) {
    __shared__ int s[256];
    int i = blockIdx.x * 256 + threadIdx.x;
    s[threadIdx.x] = (i < N_NODES) ? deg[i] : 0;
    __syncthreads();
    for (int off = 128; off > 0; off >>= 1) {
        if (threadIdx.x < off) s[threadIdx.x] += s[threadIdx.x + off];
        __syncthreads();
    }
    if (threadIdx.x == 0) bsum[blockIdx.x] = s[0];
}

__global__ __launch_bounds__(256) void scan_b(const int* __restrict__ bsum,
                                              int* __restrict__ boff) {
    __shared__ int s[256];
    int t = threadIdx.x;
    int x = (t < 196) ? bsum[t] : 0;   // 196 = ceil(50000/256) blocks in scan_a
    s[t] = x;
    __syncthreads();
    for (int off = 1; off < 256; off <<= 1) {
        int y = (t >= off) ? s[t - off] : 0;
        __syncthreads();
        s[t] += y;
        __syncthreads();
    }
    boff[t] = s[t] - x;  // exclusive prefix of block sums
}

__global__ __launch_bounds__(256) void scan_c(const int* __restrict__ deg,
                                              const int* __restrict__ boff,
                                              int* __restrict__ start) {
    __shared__ int s[256];
    int t = threadIdx.x;
    int i = blockIdx.x * 256 + t;
    int x = (i < N_NODES) ? deg[i] : 0;
    s[t] = x;
    __syncthreads();
    for (int off = 1; off < 256; off <<= 1) {
        int y = (t >= off) ? s[t - off] : 0;
        __syncthreads();
        s[t] += y;
        __syncthreads();
    }
    if (i < N_NODES) start[i] = boff[blockIdx.x] + s[t] - x;  // global exclusive scan
}

__global__ __launch_bounds__(256) void bucket_kernel(const int* __restrict__ ei,
                                                     const int* __restrict__ flag,
                                                     const int* __restrict__ start,
                                                     int* __restrict__ cursor,
                                                     int* __restrict__ eidx) {
    int e = blockIdx.x * 256 + threadIdx.x;
    if (e < N_EDGES) {
        int r, c;
        load_edge(ei, *flag, e, r, c);
        int p = start[c] + atomicAdd(&cursor[c], 1);
        eidx[p] = r;
    }
}

// v = x @ Wv^T + bv.  Tile: 64 nodes x 64 outs per block (blockIdx parity selects
// output half). W^T and x^T staged in LDS (64KB total -> 2 blocks/CU), 4x4
// register tile per thread with float4 LDS reads.
__global__ __launch_bounds__(256) void gemm_v(const float* __restrict__ x,
                                              const float* __restrict__ Wv,
                                              const float* __restrict__ bv,
                                              float* __restrict__ v) {
    __shared__ __align__(16) float wT[128 * 64];  // [i][o_local] 32KB
    __shared__ __align__(16) float xT[128 * 64];  // [i][n_local] 32KB
    int t = threadIdx.x;
    int o0 = (blockIdx.x & 1) * 64;
    int n0 = (blockIdx.x >> 1) * 64;

    #pragma unroll
    for (int k = 0; k < 32; ++k) {            // stage W slice, coalesced global read
        int q = t + k * 256;                  // q = ol*128 + i
        int ol = q >> 7, i = q & 127;
        wT[i * 64 + ol] = Wv[(o0 + ol) * 128 + i];
    }
    #pragma unroll
    for (int k = 0; k < 32; ++k) {            // stage x^T
        int q = t + k * 256;                  // q = nl*128 + i
        int nl = q >> 7, i = q & 127;
        int n = n0 + nl;
        xT[i * 64 + nl] = (n < N_NODES) ? x[n * 128 + i] : 0.0f;
    }
    __syncthreads();

    int on = t & 15;   // outputs o0 + on*4 .. +3
    int nn = t >> 4;   // nodes   n0 + nn*4 .. +3
    float acc[4][4];
    #pragma unroll
    for (int r = 0; r < 4; ++r)
        #pragma unroll
        for (int c = 0; c < 4; ++c) acc[r][c] = 0.0f;

    #pragma unroll 4
    for (int i = 0; i < 128; ++i) {
        float4 w4 = *(const float4*)&wT[i * 64 + on * 4];
        float4 x4 = *(const float4*)&xT[i * 64 + nn * 4];
        float xr[4] = {x4.x, x4.y, x4.z, x4.w};
        float wc[4] = {w4.x, w4.y, w4.z, w4.w};
        #pragma unroll
        for (int r = 0; r < 4; ++r)
            #pragma unroll
            for (int c = 0; c < 4; ++c) acc[r][c] += xr[r] * wc[c];
    }

    float4 b4 = *(const float4*)&bv[o0 + on * 4];
    float bb[4] = {b4.x, b4.y, b4.z, b4.w};
    #pragma unroll
    for (int r = 0; r < 4; ++r) {
        int n = n0 + nn * 4 + r;
        if (n < N_NODES) {
            float4 val;
            val.x = acc[r][0] + bb[0];
            val.y = acc[r][1] + bb[1];
            val.z = acc[r][2] + bb[2];
            val.w = acc[r][3] + bb[3];
            *(float4*)&v[n * 128 + o0 + on * 4] = val;
        }
    }
}

// One wave per node: lanes hold float2 channels (64*2=128), loop over incoming
// edges (eidx scalar/broadcast loads), coalesced 512B v-row reads, 2x unrolled.
__global__ __launch_bounds__(256) void gather_kernel(const float* __restrict__ v,
                                                     const int* __restrict__ start,
                                                     const int* __restrict__ deg,
                                                     const int* __restrict__ eidx,
                                                     float* __restrict__ out) {
    int lane = threadIdx.x & 63;
    int n = blockIdx.x * 4 + (threadIdx.x >> 6);   // 12500*4 = 50000 exactly
    int s0  = __builtin_amdgcn_readfirstlane(start[n]);
    int cnt = __builtin_amdgcn_readfirstlane(deg[n]);
    const float2* v2 = (const float2*)v;
    float2 a0 = {0.f, 0.f}, a1 = {0.f, 0.f};
    int j = 0;
    for (; j + 2 <= cnt; j += 2) {
        int r0 = eidx[s0 + j];
        int r1 = eidx[s0 + j + 1];
        float2 w0 = v2[(size_t)r0 * 64 + lane];
        float2 w1 = v2[(size_t)r1 * 64 + lane];
        a0.x += w0.x; a0.y += w0.y;
        a1.x += w1.x; a1.y += w1.y;
    }
    if (j < cnt) {
        int r0 = eidx[s0 + j];
        float2 w0 = v2[(size_t)r0 * 64 + lane];
        a0.x += w0.x; a0.y += w0.y;
    }
    float sc = (cnt > 0) ? 1.0f / (float)cnt : 0.0f;
    float2 res;
    res.x = (a0.x + a1.x) * sc;
    res.y = (a0.y + a1.y) * sc;
    ((float2*)out)[(size_t)n * 64 + lane] = res;
}

extern "C" void kernel_launch(void* const* d_in, const int* in_sizes, int n_in,
                              void* d_out, int out_size, void* d_ws, size_t ws_size,
                              hipStream_t stream) {
    const float* x  = (const float*)d_in[0];
    const int*   ei = (const int*)d_in[1];
    const float* Wv = (const float*)d_in[6];
    const float* bv = (const float*)d_in[7];
    float* out = (float*)d_out;

    char* ws = (char*)d_ws;
    float* v    = (float*)(ws);
    int* deg    = (int*)(ws + 25600000);
    int* cursor = (int*)(ws + 25800000);
    int* start  = (int*)(ws + 26000000);
    int* bsum   = (int*)(ws + 26200000);
    int* boff   = (int*)(ws + 26201024);
    int* flag   = (int*)(ws + 26202048);
    int* eidx   = (int*)(ws + 26203072);

    // deg + cursor are contiguous: one 400KB zeroing memset (ws is re-poisoned
    // to 0xAA before every timed launch, so this must happen every call).
    hipMemsetAsync(deg, 0, 2 * N_NODES * sizeof(int), stream);

    detect_kernel<<<1, 64, 0, stream>>>(ei, flag);
    deg_kernel<<<N_EDGES / 256, 256, 0, stream>>>(ei, flag, deg);          // 3125
    scan_a<<<196, 256, 0, stream>>>(deg, bsum);
    scan_b<<<1, 256, 0, stream>>>(bsum, boff);
    scan_c<<<196, 256, 0, stream>>>(deg, boff, start);
    bucket_kernel<<<N_EDGES / 256, 256, 0, stream>>>(ei, flag, start, cursor, eidx);
    gemm_v<<<((N_NODES + 63) / 64) * 2, 256, 0, stream>>>(x, Wv, bv, v);   // 1564
    gather_kernel<<<N_NODES / 4, 256, 0, stream>>>(v, start, deg, eidx, out);
}

// Round 2
// 275.012 us; speedup vs baseline: 1.1321x; 1.1321x over previous
//
#include <hip/hip_runtime.h>

// GAT layer N=50000, E=800000, DIN=DOUT=128, H=4.
// ALGEBRAIC SIMPLIFICATION: softmax weights per (node,head) sum to exactly 1,
// so attn_w[n,h] = 1/deg[n] for every head and
//   out[n] = (1/deg[n]) * sum_{e: col[e]=n} v[row[e]],  v = x @ Wv^T + bv.
// Wq,bq,Wk,bk,att do not affect the output.

#define N_NODES 50000
#define N_EDGES 800000

// ---- workspace layout (bytes) ----
// v      : float[50000*128]  @ 0           (25,600,000)
// deg    : int[50000]        @ 25,600,000  (zeroed by memset each call)
// cursor : int[50000]        @ 25,800,000  (initialized by scan_c)
// start  : int[50000]        @ 26,000,000
// bsum   : int[256]          @ 26,200,000
// boff   : int[256]          @ 26,201,024
// flag   : int[1]            @ 26,202,048
// eidx   : int[800000]       @ 26,203,072

// edge_index arrives as int32 or raw int64 (reference dtype); if int64 every
// high dword is 0 (values < 50000) -> detect via odd int32 slots.
__device__ __forceinline__ void load_edge(const int* __restrict__ ei, int wide, int e,
                                          int& r, int& c) {
    if (wide) { r = ei[2 * e]; c = ei[2 * N_EDGES + 2 * e]; }
    else      { r = ei[e];     c = ei[N_EDGES + e]; }
}

__global__ void detect_kernel(const int* __restrict__ ei, int* __restrict__ flag) {
    int t = threadIdx.x;  // 64 threads
    int nz = (ei[2 * t + 1] != 0) ? 1 : 0;
    unsigned long long b = __ballot(nz);
    if (t == 0) *flag = (b == 0ULL) ? 1 : 0;
}

__global__ __launch_bounds__(256) void deg_kernel(const int* __restrict__ ei,
                                                  const int* __restrict__ flag,
                                                  int* __restrict__ deg) {
    int e = blockIdx.x * 256 + threadIdx.x;
    if (e < N_EDGES) {
        int r, c;
        load_edge(ei, *flag, e, r, c);
        atomicAdd(&deg[c], 1);
    }
}

__global__ __launch_bounds__(256) void scan_a(const int* __restrict__ deg,
                                              int* __restrict__ bsum) {
    __shared__ int s[256];
    int i = blockIdx.x * 256 + threadIdx.x;
    s[threadIdx.x] = (i < N_NODES) ? deg[i] : 0;
    __syncthreads();
    for (int off = 128; off > 0; off >>= 1) {
        if (threadIdx.x < off) s[threadIdx.x] += s[threadIdx.x + off];
        __syncthreads();
    }
    if (threadIdx.x == 0) bsum[blockIdx.x] = s[0];
}

__global__ __launch_bounds__(256) void scan_b(const int* __restrict__ bsum,
                                              int* __restrict__ boff) {
    __shared__ int s[256];
    int t = threadIdx.x;
    int x = (t < 196) ? bsum[t] : 0;   // 196 = ceil(50000/256)
    s[t] = x;
    __syncthreads();
    for (int off = 1; off < 256; off <<= 1) {
        int y = (t >= off) ? s[t - off] : 0;
        __syncthreads();
        s[t] += y;
        __syncthreads();
    }
    boff[t] = s[t] - x;  // exclusive prefix of block sums
}

// Writes BOTH start[] and cursor[] (cursor starts equal to start, so bucket
// needs only one atomicAdd and no extra read).
__global__ __launch_bounds__(256) void scan_c(const int* __restrict__ deg,
                                              const int* __restrict__ boff,
                                              int* __restrict__ start,
                                              int* __restrict__ cursor) {
    __shared__ int s[256];
    int t = threadIdx.x;
    int i = blockIdx.x * 256 + t;
    int x = (i < N_NODES) ? deg[i] : 0;
    s[t] = x;
    __syncthreads();
    for (int off = 1; off < 256; off <<= 1) {
        int y = (t >= off) ? s[t - off] : 0;
        __syncthreads();
        s[t] += y;
        __syncthreads();
    }
    if (i < N_NODES) {
        int st = boff[blockIdx.x] + s[t] - x;
        start[i] = st;
        cursor[i] = st;
    }
}

__global__ __launch_bounds__(256) void bucket_kernel(const int* __restrict__ ei,
                                                     const int* __restrict__ flag,
                                                     int* __restrict__ cursor,
                                                     int* __restrict__ eidx) {
    int e = blockIdx.x * 256 + threadIdx.x;
    if (e < N_EDGES) {
        int r, c;
        load_edge(ei, *flag, e, r, c);
        int p = atomicAdd(&cursor[c], 1);
        eidx[p] = r;
    }
}

// v = x @ Wv^T + bv.
// Tile: 128 nodes x 64 outs per block (blockIdx parity = output half).
// Only W^T is staged in LDS (128 x 68-padded = 34.8KB -> up to 4 blocks/CU).
// x streams global->register, double-buffered float4; each thread owns 8 fixed
// node rows (16-lane broadcast groups -> coalesced) x 4 outs = 32 acc.
__global__ __launch_bounds__(256) void gemm_v(const float* __restrict__ x,
                                              const float* __restrict__ Wv,
                                              const float* __restrict__ bv,
                                              float* __restrict__ v) {
    __shared__ __align__(16) float wT[128 * 68];  // [i][ol], stride 68 (16B-aligned, 2-way reads)
    int t = threadIdx.x;
    int o0 = (blockIdx.x & 1) * 64;
    int n0 = (blockIdx.x >> 1) * 128;

    // Stage W^T: coalesced global reads, stride-68 LDS writes (8-way, 32 insts: cheap).
    #pragma unroll
    for (int k = 0; k < 32; ++k) {
        int q = t + k * 256;          // q = ol*128 + i
        int ol = q >> 7, i = q & 127;
        wT[i * 68 + ol] = Wv[(o0 + ol) * 128 + i];
    }
    __syncthreads();

    int on = t & 15;                  // outputs o0 + on*4 .. +3
    int g  = t >> 4;                  // node group: rows n0 + g*8 .. +7

    const float4* xrow[8];
    int rown[8];
    #pragma unroll
    for (int r = 0; r < 8; ++r) {
        int n = n0 + g * 8 + r;
        rown[r] = n;
        if (n >= N_NODES) n = N_NODES - 1;   // clamp (store is guarded)
        xrow[r] = (const float4*)(x + (size_t)n * 128);
    }

    float acc[8][4];
    #pragma unroll
    for (int r = 0; r < 8; ++r)
        #pragma unroll
        for (int c = 0; c < 4; ++c) acc[r][c] = 0.0f;

    float4 cur[8];
    #pragma unroll
    for (int r = 0; r < 8; ++r) cur[r] = xrow[r][0];

    for (int s = 0; s < 32; ++s) {
        float4 nxt[8];
        int s2 = (s < 31) ? s + 1 : 31;
        #pragma unroll
        for (int r = 0; r < 8; ++r) nxt[r] = xrow[r][s2];

        #pragma unroll
        for (int j = 0; j < 4; ++j) {
            float4 w4 = *(const float4*)&wT[(s * 4 + j) * 68 + on * 4];
            float wc[4] = {w4.x, w4.y, w4.z, w4.w};
            #pragma unroll
            for (int r = 0; r < 8; ++r) {
                float xs = ((const float*)&cur[r])[j];
                #pragma unroll
                for (int c = 0; c < 4; ++c) acc[r][c] += xs * wc[c];
            }
        }
        #pragma unroll
        for (int r = 0; r < 8; ++r) cur[r] = nxt[r];
    }

    float4 b4 = *(const float4*)&bv[o0 + on * 4];
    float bb[4] = {b4.x, b4.y, b4.z, b4.w};
    #pragma unroll
    for (int r = 0; r < 8; ++r) {
        if (rown[r] < N_NODES) {
            float4 val;
            val.x = acc[r][0] + bb[0];
            val.y = acc[r][1] + bb[1];
            val.z = acc[r][2] + bb[2];
            val.w = acc[r][3] + bb[3];
            *(float4*)&v[(size_t)rown[r] * 128 + o0 + on * 4] = val;
        }
    }
}

// One wave per node: lanes hold float2 channels (64*2=128). eidx loads are
// wave-uniform (scalarized), v-row reads are coalesced 512B. Unroll 4 for
// outstanding-load depth (L3-BW-bound stream).
__global__ __launch_bounds__(256) void gather_kernel(const float* __restrict__ v,
                                                     const int* __restrict__ start,
                                                     const int* __restrict__ deg,
                                                     const int* __restrict__ eidx,
                                                     float* __restrict__ out) {
    int lane = threadIdx.x & 63;
    int n = blockIdx.x * 4 + (threadIdx.x >> 6);   // 12500*4 = 50000 exactly
    int s0  = __builtin_amdgcn_readfirstlane(start[n]);
    int cnt = __builtin_amdgcn_readfirstlane(deg[n]);
    const float2* v2 = (const float2*)v;
    float2 a0 = {0.f, 0.f}, a1 = {0.f, 0.f}, a2 = {0.f, 0.f}, a3 = {0.f, 0.f};
    int j = 0;
    for (; j + 4 <= cnt; j += 4) {
        int r0 = eidx[s0 + j];
        int r1 = eidx[s0 + j + 1];
        int r2 = eidx[s0 + j + 2];
        int r3 = eidx[s0 + j + 3];
        float2 w0 = v2[(size_t)r0 * 64 + lane];
        float2 w1 = v2[(size_t)r1 * 64 + lane];
        float2 w2 = v2[(size_t)r2 * 64 + lane];
        float2 w3 = v2[(size_t)r3 * 64 + lane];
        a0.x += w0.x; a0.y += w0.y;
        a1.x += w1.x; a1.y += w1.y;
        a2.x += w2.x; a2.y += w2.y;
        a3.x += w3.x; a3.y += w3.y;
    }
    for (; j < cnt; ++j) {
        int r0 = eidx[s0 + j];
        float2 w0 = v2[(size_t)r0 * 64 + lane];
        a0.x += w0.x; a0.y += w0.y;
    }
    float sc = (cnt > 0) ? 1.0f / (float)cnt : 0.0f;
    float2 res;
    res.x = ((a0.x + a1.x) + (a2.x + a3.x)) * sc;
    res.y = ((a0.y + a1.y) + (a2.y + a3.y)) * sc;
    ((float2*)out)[(size_t)n * 64 + lane] = res;
}

extern "C" void kernel_launch(void* const* d_in, const int* in_sizes, int n_in,
                              void* d_out, int out_size, void* d_ws, size_t ws_size,
                              hipStream_t stream) {
    const float* x  = (const float*)d_in[0];
    const int*   ei = (const int*)d_in[1];
    const float* Wv = (const float*)d_in[6];
    const float* bv = (const float*)d_in[7];
    float* out = (float*)d_out;

    char* ws = (char*)d_ws;
    float* v    = (float*)(ws);
    int* deg    = (int*)(ws + 25600000);
    int* cursor = (int*)(ws + 25800000);
    int* start  = (int*)(ws + 26000000);
    int* bsum   = (int*)(ws + 26200000);
    int* boff   = (int*)(ws + 26201024);
    int* flag   = (int*)(ws + 26202048);
    int* eidx   = (int*)(ws + 26203072);

    // ws is re-poisoned to 0xAA before every timed launch -> zero deg each call.
    hipMemsetAsync(deg, 0, N_NODES * sizeof(int), stream);

    detect_kernel<<<1, 64, 0, stream>>>(ei, flag);
    deg_kernel<<<N_EDGES / 256, 256, 0, stream>>>(ei, flag, deg);          // 3125
    scan_a<<<196, 256, 0, stream>>>(deg, bsum);
    scan_b<<<1, 256, 0, stream>>>(bsum, boff);
    scan_c<<<196, 256, 0, stream>>>(deg, boff, start, cursor);
    bucket_kernel<<<N_EDGES / 256, 256, 0, stream>>>(ei, flag, cursor, eidx);
    gemm_v<<<((N_NODES + 127) / 128) * 2, 256, 0, stream>>>(x, Wv, bv, v); // 782
    gather_kernel<<<N_NODES / 4, 256, 0, stream>>>(v, start, deg, eidx, out);
}